// Round 17
// baseline (153.367 us; speedup 1.0000x reference)
//
#include <hip/hip_runtime.h>
#include <hip/hip_bf16.h>

#define T_SEQ 2048
#define DM 1024
#define DM2 2048
#define NH 16
#define DKH 64
#define NBATCH 4
#define MROWS (NBATCH*T_SEQ)   // 8192

typedef __attribute__((ext_vector_type(8))) short bf16x8;
typedef __attribute__((ext_vector_type(4))) short bf16x4;
typedef __attribute__((ext_vector_type(4))) float f32x4;
typedef __attribute__((ext_vector_type(16))) float f32x16;
typedef __attribute__((ext_vector_type(4))) unsigned short u16x4;

#define NEG_INF (-__builtin_inff())

#if __has_builtin(__builtin_amdgcn_exp2f)
#define EXP2(x) __builtin_amdgcn_exp2f(x)
#else
#define EXP2(x) exp2f(x)
#endif

#define MFMA32(A,B,C) __builtin_amdgcn_mfma_f32_32x32x16_bf16(A,B,C,0,0,0)

static __device__ __forceinline__ unsigned short f2bf(float f){
  union { float f; unsigned u; } v; v.f = f;
  unsigned r = v.u + 0x7fffu + ((v.u >> 16) & 1u);
  return (unsigned short)(r >> 16);
}

// RTNE float->bf16 via HW cvt (compiler fuses pairs into v_cvt_pk_bf16_f32, m240)
static __device__ __forceinline__ unsigned short f2bfc(float f){
  union { __hip_bfloat16 h; unsigned short u; } cv;
  cv.h = __float2bfloat16(f);
  return cv.u;
}

static __device__ __forceinline__ void gload_lds16(const void* g, void* l){
  __builtin_amdgcn_global_load_lds(
      (const __attribute__((address_space(1))) void*)g,
      (__attribute__((address_space(3))) void*)l, 16, 0, 0);
}

// ---------- fused prep: H fp32->bf16 (grid tail) + weight convert/transpose ----------
__global__ __launch_bounds__(256) void convprep(
    const float* __restrict__ H,
    const float* __restrict__ W0, const float* __restrict__ W1,
    const float* __restrict__ W2, const float* __restrict__ W3,
    u16x4* __restrict__ Hb4,
    unsigned short* __restrict__ O0, unsigned short* __restrict__ O1,
    unsigned short* __restrict__ O2, unsigned short* __restrict__ O3)
{
  __shared__ float t[32][33];
  const int bid = blockIdx.x, tid = threadIdx.x;
  if (bid < 4096){
    const int z = bid >> 10, rem = bid & 1023;
    const int nx = (rem & 31)*32, kx = (rem >> 5)*32;
    const float* W = (z==0)?W0:(z==1)?W1:(z==2)?W2:W3;
    unsigned short* O = (z==0)?O0:(z==1)?O1:(z==2)?O2:O3;
    const float sc = (z==0) ? 0.18033688f : 1.0f;   // log2e/8 folded into Wq
    const int tx = tid & 31, ty = tid >> 5;
    #pragma unroll
    for (int i = 0; i < 4; ++i)
      t[ty + i*8][tx] = W[(size_t)(kx + ty + i*8)*DM + nx + tx];
    __syncthreads();
    #pragma unroll
    for (int i = 0; i < 4; ++i)
      O[(size_t)(nx + ty + i*8)*DM + kx + tx] = f2bf(t[tx][ty + i*8] * sc);
  } else {
    const int n4 = MROWS*DM/4;
    for (int i = (bid - 4096)*256 + tid; i < n4; i += 2048*256){
      float4 v = ((const float4*)H)[i];
      u16x4 o;
      o[0] = f2bf(v.x); o[1] = f2bf(v.y); o[2] = f2bf(v.z); o[3] = f2bf(v.w);
      Hb4[i] = o;
    }
  }
}

// ---------------- 8-phase 256x256 GEMM (T3+T4+T5): QK projection ----------------
// Measured ~45us at this shape (R11) vs 52us for the 2-phase 128² (R14).
__global__ __launch_bounds__(512, 2) void gemm_qk8(
    const unsigned short* __restrict__ A, const unsigned short* __restrict__ Bt,
    unsigned short* __restrict__ C)
{
  __shared__ __attribute__((aligned(16))) unsigned short lds[2][32768]; // 128 KiB
  const int tid = threadIdx.x;
  const int w = tid >> 6, l = tid & 63;
  const int g = l >> 4, lr = l & 15;
  const int wr = w >> 2, wc = w & 3;
  const int bid = blockIdx.x;
  const int m0 = (bid & 31) * 256, n0 = (bid >> 5) * 256;  // m-grouped per XCD

  const int c0 = (w*2)*64 + l, c1 = (w*2+1)*64 + l;
  const int r0 = c0 >> 3, gc0 = (c0 & 7) ^ (r0 & 7);
  const int r1 = c1 >> 3, gc1 = (c1 & 7) ^ (r1 & 7);

  auto STA = [&](int h, int t, int buf){
    gload_lds16(A + (size_t)(m0 + h*128 + r0)*DM + t*64 + gc0*8,
                (char*)lds + buf*65536 + h*16384 + c0*16);
    gload_lds16(A + (size_t)(m0 + h*128 + r1)*DM + t*64 + gc1*8,
                (char*)lds + buf*65536 + h*16384 + c1*16);
  };
  auto STB = [&](int h, int t, int buf){
    gload_lds16(Bt + (size_t)(n0 + h*128 + r0)*DM + t*64 + gc0*8,
                (char*)lds + buf*65536 + 32768 + h*16384 + c0*16);
    gload_lds16(Bt + (size_t)(n0 + h*128 + r1)*DM + t*64 + gc1*8,
                (char*)lds + buf*65536 + 32768 + h*16384 + c1*16);
  };

  f32x4 acc[8][4] = {};
  bf16x8 af[8], bf[8];

  STB(0,0,0); STB(1,0,0); STA(0,0,0); STA(1,0,0);
  STB(0,1,1); STB(1,1,1); STA(0,1,1); STA(1,1,1);
  asm volatile("s_waitcnt vmcnt(8)");
  __builtin_amdgcn_s_barrier();

#define RDA(BUF, MH) do{ _Pragma("unroll") for (int mi=0;mi<4;++mi){            \
    const int ra = ((MH)*4+mi)*16 + lr;                                         \
    _Pragma("unroll") for (int kc=0;kc<2;++kc)                                  \
      af[mi*2+kc] = *(const bf16x8*)((const char*)lds + (BUF)*65536             \
        + wr*16384 + ra*128 + ((kc*64+g*16) ^ ((ra&7)<<4))); } }while(0)
#define RDB(BUF, NHI) do{ _Pragma("unroll") for (int ni=0;ni<2;++ni){           \
    const int nt = (NHI)*2+ni; const int rb = (wc&1)*64 + nt*16 + lr;           \
    _Pragma("unroll") for (int kc=0;kc<2;++kc)                                  \
      bf[nt*2+kc] = *(const bf16x8*)((const char*)lds + (BUF)*65536 + 32768     \
        + (wc>>1)*16384 + rb*128 + ((kc*64+g*16) ^ ((rb&7)<<4))); } }while(0)
#define MF(MH, NHI) do{ _Pragma("unroll") for (int mi=0;mi<4;++mi)              \
    _Pragma("unroll") for (int ni=0;ni<2;++ni)                                  \
    _Pragma("unroll") for (int kc=0;kc<2;++kc)                                  \
      acc[(MH)*4+mi][(NHI)*2+ni] = __builtin_amdgcn_mfma_f32_16x16x32_bf16(     \
        af[mi*2+kc], bf[((NHI)*2+ni)*2+kc], acc[(MH)*4+mi][(NHI)*2+ni],0,0,0); }while(0)
#define WAITL0 do{ asm volatile("s_waitcnt lgkmcnt(0)");                        \
    __builtin_amdgcn_sched_barrier(0); }while(0)

  #pragma unroll 1
  for (int i = 0; i < 8; ++i){
    const int t1 = 2*i+1, t2 = 2*i+2, t3 = 2*i+3;
    RDA(0,0); RDB(0,0);
    if (i > 0) STA(0, t1, 1);
    asm volatile("s_waitcnt lgkmcnt(8)");
    __builtin_amdgcn_s_barrier();
    WAITL0;
    __builtin_amdgcn_s_setprio(1); MF(0,0); __builtin_amdgcn_s_setprio(0);
    __builtin_amdgcn_s_barrier();
    RDB(0,1);
    if (i > 0) STA(1, t1, 1);
    __builtin_amdgcn_s_barrier();
    WAITL0;
    __builtin_amdgcn_s_setprio(1); MF(0,1); __builtin_amdgcn_s_setprio(0);
    __builtin_amdgcn_s_barrier();
    RDA(0,1);
    if (i < 7) STB(0, t2, 0);
    __builtin_amdgcn_s_barrier();
    WAITL0;
    __builtin_amdgcn_s_setprio(1); MF(1,1); __builtin_amdgcn_s_setprio(0);
    __builtin_amdgcn_s_barrier();
    if (i < 7) STB(1, t2, 0);
    __builtin_amdgcn_s_setprio(1); MF(1,0); __builtin_amdgcn_s_setprio(0);
    if (i < 7) asm volatile("s_waitcnt vmcnt(4)");
    else       asm volatile("s_waitcnt vmcnt(0)");
    __builtin_amdgcn_s_barrier();
    RDA(1,0); RDB(1,0);
    if (i < 7) STA(0, t2, 0);
    asm volatile("s_waitcnt lgkmcnt(8)");
    __builtin_amdgcn_s_barrier();
    WAITL0;
    __builtin_amdgcn_s_setprio(1); MF(0,0); __builtin_amdgcn_s_setprio(0);
    __builtin_amdgcn_s_barrier();
    RDB(1,1);
    if (i < 7) STA(1, t2, 0);
    __builtin_amdgcn_s_barrier();
    WAITL0;
    __builtin_amdgcn_s_setprio(1); MF(0,1); __builtin_amdgcn_s_setprio(0);
    __builtin_amdgcn_s_barrier();
    RDA(1,1);
    if (i < 7) STB(0, t3, 1);
    __builtin_amdgcn_s_barrier();
    WAITL0;
    __builtin_amdgcn_s_setprio(1); MF(1,1); __builtin_amdgcn_s_setprio(0);
    __builtin_amdgcn_s_barrier();
    if (i < 7) STB(1, t3, 1);
    __builtin_amdgcn_s_setprio(1); MF(1,0); __builtin_amdgcn_s_setprio(0);
    asm volatile("s_waitcnt vmcnt(4)");
    __builtin_amdgcn_s_barrier();
  }
#undef RDA
#undef RDB
#undef MF
#undef WAITL0

  #pragma unroll
  for (int mt = 0; mt < 8; ++mt){
    const int row_b = m0 + wr*128 + mt*16 + 4*g;
    #pragma unroll
    for (int nt = 0; nt < 4; ++nt){
      const int col = n0 + wc*64 + nt*16 + lr;
      #pragma unroll
      for (int r = 0; r < 4; ++r)
        C[(size_t)(row_b + r)*DM2 + col] = f2bf(acc[mt][nt][r]);
    }
  }
}

// ---------------- 128x128 2-phase GEMM core (Vt + output GEMMs) ----------------
template<bool F32OUT>
static __device__ __forceinline__ void gemm_body(
    const unsigned short* __restrict__ A, const unsigned short* __restrict__ Bt,
    void* __restrict__ Cp, int N, int K, int m0, int n0,
    unsigned short* a_lds, unsigned short* b_lds)
{
  const int tid = threadIdx.x;
  const int w = tid >> 6, l = tid & 63;
  const int g = l >> 4, lr = l & 15;
  const int wr = w >> 1, wc = w & 1;
  f32x4 acc[4][4] = {};
  const int nk = K >> 6;
  for (int ks = 0; ks < nk; ++ks){
    __syncthreads();
    const int k0 = ks << 6;
    #pragma unroll
    for (int i = 0; i < 4; ++i){
      int c = (w*4 + i)*64 + l;
      int row = c >> 3;
      int gc = (c & 7) ^ (row & 7);
      gload_lds16(A + (size_t)(m0 + row)*K + (k0 + gc*8), &a_lds[c*8]);
    }
    #pragma unroll
    for (int i = 0; i < 4; ++i){
      int c = (w*4 + i)*64 + l;
      int row = c >> 3;
      int gc = (c & 7) ^ (row & 7);
      gload_lds16(Bt + (size_t)(n0 + row)*K + (k0 + gc*8), &b_lds[c*8]);
    }
    __syncthreads();
    #pragma unroll
    for (int kc = 0; kc < 2; ++kc){
      bf16x8 af[4], bf_[4];
      #pragma unroll
      for (int mt = 0; mt < 4; ++mt){
        int row = wr*64 + mt*16 + lr;
        int off = row*128 + ((kc*64 + g*16) ^ ((row & 7) << 4));
        af[mt] = *(const bf16x8*)((const char*)a_lds + off);
      }
      #pragma unroll
      for (int nt = 0; nt < 4; ++nt){
        int row = wc*64 + nt*16 + lr;
        int off = row*128 + ((kc*64 + g*16) ^ ((row & 7) << 4));
        bf_[nt] = *(const bf16x8*)((const char*)b_lds + off);
      }
      #pragma unroll
      for (int mt = 0; mt < 4; ++mt)
        #pragma unroll
        for (int nt = 0; nt < 4; ++nt)
          acc[mt][nt] = __builtin_amdgcn_mfma_f32_16x16x32_bf16(af[mt], bf_[nt], acc[mt][nt], 0, 0, 0);
    }
  }
  #pragma unroll
  for (int mt = 0; mt < 4; ++mt){
    #pragma unroll
    for (int nt = 0; nt < 4; ++nt){
      const int col = n0 + wc*64 + nt*16 + lr;
      #pragma unroll
      for (int r = 0; r < 4; ++r){
        const int row = m0 + wr*64 + mt*16 + 4*g + r;   // C/D: col=lane&15, row=(lane>>4)*4+r (m89)
        if (F32OUT) ((float*)Cp)[(size_t)row*N + col] = acc[mt][nt][r];
        else ((unsigned short*)Cp)[(size_t)row*N + col] = f2bf(acc[mt][nt][r]);
      }
    }
  }
}

// V^T projection: Vt[1024][8192] = Wvt @ Hb^T
__global__ __launch_bounds__(256) void gemm_vt(
    const unsigned short* __restrict__ Wvt, const unsigned short* __restrict__ Hb,
    unsigned short* __restrict__ Vtb)
{
  __shared__ __attribute__((aligned(16))) unsigned short a_lds[128*64];
  __shared__ __attribute__((aligned(16))) unsigned short b_lds[128*64];
  gemm_body<false>(Wvt, Hb, Vtb, MROWS, DM, blockIdx.x*128, blockIdx.y*128, a_lds, b_lds);
}

// Output GEMM: d_out[8192][1024] fp32 = Ab @ Wo^T
__global__ __launch_bounds__(256) void gemm_out(
    const unsigned short* __restrict__ Ab, const unsigned short* __restrict__ Wot,
    float* __restrict__ Out)
{
  __shared__ __attribute__((aligned(16))) unsigned short a_lds[128*64];
  __shared__ __attribute__((aligned(16))) unsigned short b_lds[128*64];
  gemm_body<true>(Ab, Wot, Out, DM, DM, blockIdx.x*128, blockIdx.y*128, a_lds, b_lds);
}

// ---- per-64kv-half softmax (exp2 domain; T13 defer-max THR=8; VALU denominator) ----
static __device__ __forceinline__ void half_softmax(
    f32x16& st0, f32x16& st1, float& m_run, float& l_run,
    f32x16& acc0, f32x16& acc1, bf16x8 (&pb)[4],
    int kvb, int qg, bool fullT)
{
  if (!fullT){
    #pragma unroll
    for (int r = 0; r < 16; ++r){
      const int kvo = (r & 3) + 4*((r >> 2) & 1) + 16*(r >> 3);
      st0[r] = (kvb + kvo      <= qg) ? st0[r] : NEG_INF;
      st1[r] = (kvb + 32 + kvo <= qg) ? st1[r] : NEG_INF;
    }
  }
  float m01[8];
  #pragma unroll
  for (int r = 0; r < 8; ++r)
    m01[r] = fmaxf(fmaxf(st0[2*r], st0[2*r+1]), fmaxf(st1[2*r], st1[2*r+1]));
  float tm = fmaxf(fmaxf(fmaxf(m01[0],m01[1]), fmaxf(m01[2],m01[3])),
                   fmaxf(fmaxf(m01[4],m01[5]), fmaxf(m01[6],m01[7])));
  float mm = m_run;
  if (!__all(tm - m_run <= 8.f)){                 // first tile: inf/NaN -> rescale path
    float tg = fmaxf(tm, __shfl_xor(tm, 32));     // partner lane = same q row, other k-half
    const float mn = fmaxf(m_run, tg);
    const float fac = EXP2(m_run - mn);           // first tile: exp2(-inf)=0
    l_run *= fac;
    #pragma unroll
    for (int r = 0; r < 16; ++r){ acc0[r] *= fac; acc1[r] *= fac; }
    m_run = mn; mm = mn;
  }
  float ps0 = 0.f, ps1 = 0.f, ps2 = 0.f, ps3 = 0.f;
  #pragma unroll
  for (int r = 0; r < 4; ++r){
    float e0 = EXP2(st0[4*r+0]-mm), e1 = EXP2(st0[4*r+1]-mm);
    float e2 = EXP2(st0[4*r+2]-mm), e3 = EXP2(st0[4*r+3]-mm);
    float f0 = EXP2(st1[4*r+0]-mm), f1 = EXP2(st1[4*r+1]-mm);
    float f2 = EXP2(st1[4*r+2]-mm), f3 = EXP2(st1[4*r+3]-mm);
    ps0 += e0 + f0; ps1 += e1 + f1; ps2 += e2 + f2; ps3 += e3 + f3;
    st0[4*r+0]=e0; st0[4*r+1]=e1; st0[4*r+2]=e2; st0[4*r+3]=e3;
    st1[4*r+0]=f0; st1[4*r+1]=f1; st1[4*r+2]=f2; st1[4*r+3]=f3;
  }
  l_run += (ps0 + ps1) + (ps2 + ps3);             // lane-local partial; cross-half at epilogue
  #pragma unroll
  for (int m = 0; m < 2; ++m){
    bf16x8 t0, t1;
    #pragma unroll
    for (int i = 0; i < 8; ++i){
      t0[i] = (short)f2bfc(st0[8*m+i]);
      t1[i] = (short)f2bfc(st1[8*m+i]);
    }
    pb[m] = t0; pb[2+m] = t1;
  }
}

// ---------------- causal flash attention (32x32 MFMA, KVBLK=256) ----------------
// R17: R11 structure with KVBLK 128->256 (parameter change; ROUND template,
// sigma-permuted K placement, swizzles, softmax identical). Rounds/block 18->9
// (uniform: heavy 8-p + light p+1 = 9 for all p): halves the per-round barrier/
// chain fixed cost while total LDS/MFMA/VALU work is unchanged. LDS 128KB
// (2buf x {K 256x64, V 64x256}) -> still 1 block/CU (grid 256 = 1/CU already).
__global__ __launch_bounds__(512, 2) void attn_kernel(const unsigned short* __restrict__ QK,
                                                      const unsigned short* __restrict__ Vt,
                                                      unsigned short* __restrict__ Og)
{
  __shared__ __attribute__((aligned(16))) unsigned short k_lds[2][256*64];
  __shared__ __attribute__((aligned(16))) unsigned short v_lds[2][64*256];
  const int tid = threadIdx.x;
  const int w = tid >> 6, l = tid & 63;
  const int h1 = l >> 5, lq = l & 31;
  const int L = blockIdx.x;
  const int xcd = L & 7, idx = L >> 3;
  const int bh = xcd*8 + (idx & 7);
  const int p = idx >> 3;                               // 0..3
  const int b = bh >> 4, h = bh & 15;
  const size_t baseK = (size_t)(b*T_SEQ)*DM2 + 1024 + h*DKH;
  const size_t baseV = (size_t)(h*DKH)*MROWS + (size_t)b*T_SEQ;

  // staging geometry: K 2048 + V 2048 16B chunks/round, 4+4 per thread.
  // K row kr (0..255) holds kv = j0 + kappa(kr) (sigma placement, as R11);
  // V rows are 64 dk x 256 kv = 32 chunks/row, XOR-swizzled on low 4 chunk bits.
  int kvp[4], kip[4], vrp[4], vgp[4];
  #pragma unroll
  for (int i = 0; i < 4; ++i){
    const int c = tid + 512*i;
    const int kr = c >> 3;
    kip[i] = (c & 7) ^ (kr & 7);
    kvp[i] = 32*(kr >> 5) + 16*((kr >> 4) & 1) + 8*((kr >> 2) & 1) + 4*((kr >> 3) & 1) + (kr & 3);
    const int vr = c >> 5;
    vrp[i] = vr;
    vgp[i] = (c & 31) ^ (vr & 15);
  }

  auto STAGE = [&](int jt, int buf){
    const int j0s = jt * 256;
    #pragma unroll
    for (int i = 0; i < 4; ++i){
      const int c = tid + 512*i;
      gload_lds16(QK + baseK + (size_t)(j0s + kvp[i])*DM2 + kip[i]*8, &k_lds[buf][c*8]);
      gload_lds16(Vt + baseV + (size_t)vrp[i]*MROWS + j0s + vgp[i]*8, &v_lds[buf][c*8]);
    }
  };

#define ROUND(JT, CUR) do{                                                        \
    const int jt_ = (JT);                                                         \
    if (jt_ + 1 < ntiles) STAGE(jt_ + 1, (CUR)^1);                                \
    const int j0_ = jt_ * 256;                                                    \
    _Pragma("unroll")                                                             \
    for (int h2 = 0; h2 < 4; ++h2){                                               \
      if (j0_ + 64*h2 <= qhi){                                                    \
        f32x16 st0 = {}, st1 = {};                                                \
        __builtin_amdgcn_s_setprio(1);                                            \
        _Pragma("unroll")                                                         \
        for (int s = 0; s < 4; ++s){                                              \
          const int r0_ = 64*h2 + lq, r1_ = r0_ + 32;                             \
          bf16x8 kf0 = *(const bf16x8*)((const char*)k_lds[CUR] + r0_*128 + (((2*s + h1) ^ (r0_ & 7)) << 4)); \
          bf16x8 kf1 = *(const bf16x8*)((const char*)k_lds[CUR] + r1_*128 + (((2*s + h1) ^ (r1_ & 7)) << 4)); \
          st0 = MFMA32(kf0, qf[s], st0);                                          \
          st1 = MFMA32(kf1, qf[s], st1);                                          \
        }                                                                         \
        __builtin_amdgcn_s_setprio(0);                                            \
        bf16x8 pb[4];                                                             \
        half_softmax(st0, st1, m_run, l_run, acc0, acc1, pb,                      \
                     j0_ + 64*h2 + 8*h1, qg, (j0_ + 64*h2 + 63) <= qlo);          \
        __builtin_amdgcn_s_setprio(1);                                            \
        _Pragma("unroll")                                                         \
        for (int jl = 0; jl < 4; ++jl){                                           \
          const int vr0 = lq, vr1 = 32 + lq;                                      \
          bf16x8 vf0 = *(const bf16x8*)((const char*)v_lds[CUR] + vr0*512 + (((2*(4*h2 + jl) + h1) ^ (vr0 & 15)) << 4)); \
          bf16x8 vf1 = *(const bf16x8*)((const char*)v_lds[CUR] + vr1*512 + (((2*(4*h2 + jl) + h1) ^ (vr1 & 15)) << 4)); \
          acc0 = MFMA32(vf0, pb[jl], acc0);                                       \
          acc1 = MFMA32(vf1, pb[jl], acc1);                                       \
        }                                                                         \
        __builtin_amdgcn_s_setprio(0);                                            \
      }                                                                           \
    }                                                                             \
    __syncthreads();                                                              \
  } while(0)

  #pragma unroll 1
  for (int seg = 0; seg < 2; ++seg){
    const int qblk = seg ? p : (7 - p);                 // heavy then light: 9 rounds total
    const int q0 = qblk * 256;
    const int qlo = q0 + 32*w;
    const int qhi = qlo + 31;
    const int qg = qlo + lq;
    const size_t rowQ = (size_t)(b*T_SEQ + qg)*DM2 + h*DKH;
    bf16x8 qf[4];
    #pragma unroll
    for (int s = 0; s < 4; ++s)
      qf[s] = *(const bf16x8*)(QK + rowQ + 16*s + 8*h1);
    float m_run = NEG_INF, l_run = 0.f;
    f32x16 acc0 = {}, acc1 = {};
    const int ntiles = qblk + 1;                        // tiles of 256 kv

    STAGE(0, 0);
    __syncthreads();

    int jt = 0;
    #pragma unroll 1
    for (; jt + 2 <= ntiles; jt += 2){
      ROUND(jt, 0);
      ROUND(jt + 1, 1);
    }
    if (jt < ntiles) ROUND(jt, 0);                      // odd ntiles -> tail on buf0

    const float ls = l_run + __shfl_xor(l_run, 32);
    const float inv = 1.f / ls;
    const size_t rowO = (size_t)(b*T_SEQ + qg)*DM + h*DKH;
    #pragma unroll
    for (int d = 0; d < 2; ++d){
      const f32x16& Aq = d ? acc1 : acc0;
      #pragma unroll
      for (int bb = 0; bb < 4; ++bb){
        unsigned u0 = (unsigned)f2bfc(Aq[4*bb+0]*inv) | ((unsigned)f2bfc(Aq[4*bb+1]*inv) << 16);
        unsigned u1 = (unsigned)f2bfc(Aq[4*bb+2]*inv) | ((unsigned)f2bfc(Aq[4*bb+3]*inv) << 16);
        uint2 uv; uv.x = u0; uv.y = u1;
        *(uint2*)(Og + rowO + 32*d + 8*bb + 4*h1) = uv;
      }
    }
    // seg boundary: ROUND ends with __syncthreads -> safe to re-STAGE buf0.
  }
#undef ROUND
}

// ---------------- launch ----------------
extern "C" void kernel_launch(void* const* d_in, const int* in_sizes, int n_in,
                              void* d_out, int out_size, void* d_ws, size_t ws_size,
                              hipStream_t stream)
{
  (void)in_sizes; (void)n_in; (void)out_size; (void)ws_size;
  const float* H  = (const float*)d_in[0];
  const float* Wq = (const float*)d_in[1];
  const float* Wk = (const float*)d_in[2];
  const float* Wv = (const float*)d_in[3];
  const float* Wo = (const float*)d_in[4];
  char* ws = (char*)d_ws;
  unsigned short* Hb   = (unsigned short*)(ws);
  unsigned short* Wqkt = (unsigned short*)(ws + 16777216);   // rows 0-1023: Wq^T (scaled), 1024-2047: Wk^T
  unsigned short* Wkt  = (unsigned short*)(ws + 18874368);
  unsigned short* Wvt  = (unsigned short*)(ws + 20971520);
  unsigned short* Wot  = (unsigned short*)(ws + 23068672);
  unsigned short* QKb  = (unsigned short*)(ws + 25165824);   // 32MB
  unsigned short* Vtb  = (unsigned short*)(ws + 58720256);
  unsigned short* Ab   = (unsigned short*)(ws + 75497472);

  convprep<<<6144, 256, 0, stream>>>(H, Wq, Wk, Wv, Wo,
                                     (u16x4*)Hb, Wqkt, Wkt, Wvt, Wot);
  gemm_qk8<<<256, 512, 0, stream>>>(Hb, Wqkt, QKb);
  gemm_vt<<<dim3(8,64), 256, 0, stream>>>(Wvt, Hb, Vtb);
  attn_kernel<<<dim3(256), 512, 0, stream>>>(QKb, Vtb, Ab);
  gemm_out<<<dim3(64,8), 256, 0, stream>>>(Ab, Wot, (float*)d_out);
}

// Round 18
// 152.403 us; speedup vs baseline: 1.0063x; 1.0063x over previous
//
#include <hip/hip_runtime.h>
#include <hip/hip_bf16.h>

#define T_SEQ 2048
#define DM 1024
#define DM2 2048
#define NH 16
#define DKH 64
#define NBATCH 4
#define MROWS (NBATCH*T_SEQ)   // 8192

typedef __attribute__((ext_vector_type(8))) short bf16x8;
typedef __attribute__((ext_vector_type(4))) short bf16x4;
typedef __attribute__((ext_vector_type(4))) float f32x4;
typedef __attribute__((ext_vector_type(16))) float f32x16;
typedef __attribute__((ext_vector_type(4))) unsigned short u16x4;

#define NEG_INF (-__builtin_inff())

#if __has_builtin(__builtin_amdgcn_exp2f)
#define EXP2(x) __builtin_amdgcn_exp2f(x)
#else
#define EXP2(x) exp2f(x)
#endif

#define MFMA32(A,B,C) __builtin_amdgcn_mfma_f32_32x32x16_bf16(A,B,C,0,0,0)

static __device__ __forceinline__ unsigned short f2bf(float f){
  union { float f; unsigned u; } v; v.f = f;
  unsigned r = v.u + 0x7fffu + ((v.u >> 16) & 1u);
  return (unsigned short)(r >> 16);
}

// RTNE float->bf16 via HW cvt (compiler fuses pairs into v_cvt_pk_bf16_f32, m240)
static __device__ __forceinline__ unsigned short f2bfc(float f){
  union { __hip_bfloat16 h; unsigned short u; } cv;
  cv.h = __float2bfloat16(f);
  return cv.u;
}

static __device__ __forceinline__ void gload_lds16(const void* g, void* l){
  __builtin_amdgcn_global_load_lds(
      (const __attribute__((address_space(1))) void*)g,
      (__attribute__((address_space(3))) void*)l, 16, 0, 0);
}

// ---------- fused prep: H fp32->bf16 (grid tail) + weight convert/transpose ----------
__global__ __launch_bounds__(256) void convprep(
    const float* __restrict__ H,
    const float* __restrict__ W0, const float* __restrict__ W1,
    const float* __restrict__ W2, const float* __restrict__ W3,
    u16x4* __restrict__ Hb4,
    unsigned short* __restrict__ O0, unsigned short* __restrict__ O1,
    unsigned short* __restrict__ O2, unsigned short* __restrict__ O3)
{
  __shared__ float t[32][33];
  const int bid = blockIdx.x, tid = threadIdx.x;
  if (bid < 4096){
    const int z = bid >> 10, rem = bid & 1023;
    const int nx = (rem & 31)*32, kx = (rem >> 5)*32;
    const float* W = (z==0)?W0:(z==1)?W1:(z==2)?W2:W3;
    unsigned short* O = (z==0)?O0:(z==1)?O1:(z==2)?O2:O3;
    const float sc = (z==0) ? 0.18033688f : 1.0f;   // log2e/8 folded into Wq
    const int tx = tid & 31, ty = tid >> 5;
    #pragma unroll
    for (int i = 0; i < 4; ++i)
      t[ty + i*8][tx] = W[(size_t)(kx + ty + i*8)*DM + nx + tx];
    __syncthreads();
    #pragma unroll
    for (int i = 0; i < 4; ++i)
      O[(size_t)(nx + ty + i*8)*DM + kx + tx] = f2bf(t[tx][ty + i*8] * sc);
  } else {
    const int n4 = MROWS*DM/4;
    for (int i = (bid - 4096)*256 + tid; i < n4; i += 2048*256){
      float4 v = ((const float4*)H)[i];
      u16x4 o;
      o[0] = f2bf(v.x); o[1] = f2bf(v.y); o[2] = f2bf(v.z); o[3] = f2bf(v.w);
      Hb4[i] = o;
    }
  }
}

// ---------------- 8-phase 256x256 GEMM (T3+T4+T5): QK projection ----------------
// Measured ~45us at this shape (R11) vs 52us for the 2-phase 128² (R14).
__global__ __launch_bounds__(512, 2) void gemm_qk8(
    const unsigned short* __restrict__ A, const unsigned short* __restrict__ Bt,
    unsigned short* __restrict__ C)
{
  __shared__ __attribute__((aligned(16))) unsigned short lds[2][32768]; // 128 KiB
  const int tid = threadIdx.x;
  const int w = tid >> 6, l = tid & 63;
  const int g = l >> 4, lr = l & 15;
  const int wr = w >> 2, wc = w & 3;
  const int bid = blockIdx.x;
  const int m0 = (bid & 31) * 256, n0 = (bid >> 5) * 256;  // m-grouped per XCD

  const int c0 = (w*2)*64 + l, c1 = (w*2+1)*64 + l;
  const int r0 = c0 >> 3, gc0 = (c0 & 7) ^ (r0 & 7);
  const int r1 = c1 >> 3, gc1 = (c1 & 7) ^ (r1 & 7);

  auto STA = [&](int h, int t, int buf){
    gload_lds16(A + (size_t)(m0 + h*128 + r0)*DM + t*64 + gc0*8,
                (char*)lds + buf*65536 + h*16384 + c0*16);
    gload_lds16(A + (size_t)(m0 + h*128 + r1)*DM + t*64 + gc1*8,
                (char*)lds + buf*65536 + h*16384 + c1*16);
  };
  auto STB = [&](int h, int t, int buf){
    gload_lds16(Bt + (size_t)(n0 + h*128 + r0)*DM + t*64 + gc0*8,
                (char*)lds + buf*65536 + 32768 + h*16384 + c0*16);
    gload_lds16(Bt + (size_t)(n0 + h*128 + r1)*DM + t*64 + gc1*8,
                (char*)lds + buf*65536 + 32768 + h*16384 + c1*16);
  };

  f32x4 acc[8][4] = {};
  bf16x8 af[8], bf[8];

  STB(0,0,0); STB(1,0,0); STA(0,0,0); STA(1,0,0);
  STB(0,1,1); STB(1,1,1); STA(0,1,1); STA(1,1,1);
  asm volatile("s_waitcnt vmcnt(8)");
  __builtin_amdgcn_s_barrier();

#define RDA(BUF, MH) do{ _Pragma("unroll") for (int mi=0;mi<4;++mi){            \
    const int ra = ((MH)*4+mi)*16 + lr;                                         \
    _Pragma("unroll") for (int kc=0;kc<2;++kc)                                  \
      af[mi*2+kc] = *(const bf16x8*)((const char*)lds + (BUF)*65536             \
        + wr*16384 + ra*128 + ((kc*64+g*16) ^ ((ra&7)<<4))); } }while(0)
#define RDB(BUF, NHI) do{ _Pragma("unroll") for (int ni=0;ni<2;++ni){           \
    const int nt = (NHI)*2+ni; const int rb = (wc&1)*64 + nt*16 + lr;           \
    _Pragma("unroll") for (int kc=0;kc<2;++kc)                                  \
      bf[nt*2+kc] = *(const bf16x8*)((const char*)lds + (BUF)*65536 + 32768     \
        + (wc>>1)*16384 + rb*128 + ((kc*64+g*16) ^ ((rb&7)<<4))); } }while(0)
#define MF(MH, NHI) do{ _Pragma("unroll") for (int mi=0;mi<4;++mi)              \
    _Pragma("unroll") for (int ni=0;ni<2;++ni)                                  \
    _Pragma("unroll") for (int kc=0;kc<2;++kc)                                  \
      acc[(MH)*4+mi][(NHI)*2+ni] = __builtin_amdgcn_mfma_f32_16x16x32_bf16(     \
        af[mi*2+kc], bf[((NHI)*2+ni)*2+kc], acc[(MH)*4+mi][(NHI)*2+ni],0,0,0); }while(0)
#define WAITL0 do{ asm volatile("s_waitcnt lgkmcnt(0)");                        \
    __builtin_amdgcn_sched_barrier(0); }while(0)

  #pragma unroll 1
  for (int i = 0; i < 8; ++i){
    const int t1 = 2*i+1, t2 = 2*i+2, t3 = 2*i+3;
    RDA(0,0); RDB(0,0);
    if (i > 0) STA(0, t1, 1);
    asm volatile("s_waitcnt lgkmcnt(8)");
    __builtin_amdgcn_s_barrier();
    WAITL0;
    __builtin_amdgcn_s_setprio(1); MF(0,0); __builtin_amdgcn_s_setprio(0);
    __builtin_amdgcn_s_barrier();
    RDB(0,1);
    if (i > 0) STA(1, t1, 1);
    __builtin_amdgcn_s_barrier();
    WAITL0;
    __builtin_amdgcn_s_setprio(1); MF(0,1); __builtin_amdgcn_s_setprio(0);
    __builtin_amdgcn_s_barrier();
    RDA(0,1);
    if (i < 7) STB(0, t2, 0);
    __builtin_amdgcn_s_barrier();
    WAITL0;
    __builtin_amdgcn_s_setprio(1); MF(1,1); __builtin_amdgcn_s_setprio(0);
    __builtin_amdgcn_s_barrier();
    if (i < 7) STB(1, t2, 0);
    __builtin_amdgcn_s_setprio(1); MF(1,0); __builtin_amdgcn_s_setprio(0);
    if (i < 7) asm volatile("s_waitcnt vmcnt(4)");
    else       asm volatile("s_waitcnt vmcnt(0)");
    __builtin_amdgcn_s_barrier();
    RDA(1,0); RDB(1,0);
    if (i < 7) STA(0, t2, 0);
    asm volatile("s_waitcnt lgkmcnt(8)");
    __builtin_amdgcn_s_barrier();
    WAITL0;
    __builtin_amdgcn_s_setprio(1); MF(0,0); __builtin_amdgcn_s_setprio(0);
    __builtin_amdgcn_s_barrier();
    RDB(1,1);
    if (i < 7) STA(1, t2, 0);
    __builtin_amdgcn_s_barrier();
    WAITL0;
    __builtin_amdgcn_s_setprio(1); MF(0,1); __builtin_amdgcn_s_setprio(0);
    __builtin_amdgcn_s_barrier();
    RDA(1,1);
    if (i < 7) STB(0, t3, 1);
    __builtin_amdgcn_s_barrier();
    WAITL0;
    __builtin_amdgcn_s_setprio(1); MF(1,1); __builtin_amdgcn_s_setprio(0);
    __builtin_amdgcn_s_barrier();
    if (i < 7) STB(1, t3, 1);
    __builtin_amdgcn_s_setprio(1); MF(1,0); __builtin_amdgcn_s_setprio(0);
    asm volatile("s_waitcnt vmcnt(4)");
    __builtin_amdgcn_s_barrier();
  }
#undef RDA
#undef RDB
#undef MF
#undef WAITL0

  #pragma unroll
  for (int mt = 0; mt < 8; ++mt){
    const int row_b = m0 + wr*128 + mt*16 + 4*g;
    #pragma unroll
    for (int nt = 0; nt < 4; ++nt){
      const int col = n0 + wc*64 + nt*16 + lr;
      #pragma unroll
      for (int r = 0; r < 4; ++r)
        C[(size_t)(row_b + r)*DM2 + col] = f2bf(acc[mt][nt][r]);
    }
  }
}

// ---------------- 128x128 2-phase GEMM core (Vt + output GEMMs) ----------------
template<bool F32OUT>
static __device__ __forceinline__ void gemm_body(
    const unsigned short* __restrict__ A, const unsigned short* __restrict__ Bt,
    void* __restrict__ Cp, int N, int K, int m0, int n0,
    unsigned short* a_lds, unsigned short* b_lds)
{
  const int tid = threadIdx.x;
  const int w = tid >> 6, l = tid & 63;
  const int g = l >> 4, lr = l & 15;
  const int wr = w >> 1, wc = w & 1;
  f32x4 acc[4][4] = {};
  const int nk = K >> 6;
  for (int ks = 0; ks < nk; ++ks){
    __syncthreads();
    const int k0 = ks << 6;
    #pragma unroll
    for (int i = 0; i < 4; ++i){
      int c = (w*4 + i)*64 + l;
      int row = c >> 3;
      int gc = (c & 7) ^ (row & 7);
      gload_lds16(A + (size_t)(m0 + row)*K + (k0 + gc*8), &a_lds[c*8]);
    }
    #pragma unroll
    for (int i = 0; i < 4; ++i){
      int c = (w*4 + i)*64 + l;
      int row = c >> 3;
      int gc = (c & 7) ^ (row & 7);
      gload_lds16(Bt + (size_t)(n0 + row)*K + (k0 + gc*8), &b_lds[c*8]);
    }
    __syncthreads();
    #pragma unroll
    for (int kc = 0; kc < 2; ++kc){
      bf16x8 af[4], bf_[4];
      #pragma unroll
      for (int mt = 0; mt < 4; ++mt){
        int row = wr*64 + mt*16 + lr;
        int off = row*128 + ((kc*64 + g*16) ^ ((row & 7) << 4));
        af[mt] = *(const bf16x8*)((const char*)a_lds + off);
      }
      #pragma unroll
      for (int nt = 0; nt < 4; ++nt){
        int row = wc*64 + nt*16 + lr;
        int off = row*128 + ((kc*64 + g*16) ^ ((row & 7) << 4));
        bf_[nt] = *(const bf16x8*)((const char*)b_lds + off);
      }
      #pragma unroll
      for (int mt = 0; mt < 4; ++mt)
        #pragma unroll
        for (int nt = 0; nt < 4; ++nt)
          acc[mt][nt] = __builtin_amdgcn_mfma_f32_16x16x32_bf16(af[mt], bf_[nt], acc[mt][nt], 0, 0, 0);
    }
  }
  #pragma unroll
  for (int mt = 0; mt < 4; ++mt){
    #pragma unroll
    for (int nt = 0; nt < 4; ++nt){
      const int col = n0 + wc*64 + nt*16 + lr;
      #pragma unroll
      for (int r = 0; r < 4; ++r){
        const int row = m0 + wr*64 + mt*16 + 4*g + r;   // C/D: col=lane&15, row=(lane>>4)*4+r (m89)
        if (F32OUT) ((float*)Cp)[(size_t)row*N + col] = acc[mt][nt][r];
        else ((unsigned short*)Cp)[(size_t)row*N + col] = f2bf(acc[mt][nt][r]);
      }
    }
  }
}

// V^T projection: Vt[1024][8192] = Wvt @ Hb^T
__global__ __launch_bounds__(256) void gemm_vt(
    const unsigned short* __restrict__ Wvt, const unsigned short* __restrict__ Hb,
    unsigned short* __restrict__ Vtb)
{
  __shared__ __attribute__((aligned(16))) unsigned short a_lds[128*64];
  __shared__ __attribute__((aligned(16))) unsigned short b_lds[128*64];
  gemm_body<false>(Wvt, Hb, Vtb, MROWS, DM, blockIdx.x*128, blockIdx.y*128, a_lds, b_lds);
}

// Output GEMM: d_out[8192][1024] fp32 = Ab @ Wo^T
__global__ __launch_bounds__(256) void gemm_out(
    const unsigned short* __restrict__ Ab, const unsigned short* __restrict__ Wot,
    float* __restrict__ Out)
{
  __shared__ __attribute__((aligned(16))) unsigned short a_lds[128*64];
  __shared__ __attribute__((aligned(16))) unsigned short b_lds[128*64];
  gemm_body<true>(Ab, Wot, Out, DM, DM, blockIdx.x*128, blockIdx.y*128, a_lds, b_lds);
}

// ---- per-64kv-half softmax (exp2 domain; T13 defer-max THR=8; VALU denominator) ----
static __device__ __forceinline__ void half_softmax(
    f32x16& st0, f32x16& st1, float& m_run, float& l_run,
    f32x16& acc0, f32x16& acc1, bf16x8 (&pb)[4],
    int kvb, int qg, bool fullT)
{
  if (!fullT){
    #pragma unroll
    for (int r = 0; r < 16; ++r){
      const int kvo = (r & 3) + 4*((r >> 2) & 1) + 16*(r >> 3);
      st0[r] = (kvb + kvo      <= qg) ? st0[r] : NEG_INF;
      st1[r] = (kvb + 32 + kvo <= qg) ? st1[r] : NEG_INF;
    }
  }
  float m01[8];
  #pragma unroll
  for (int r = 0; r < 8; ++r)
    m01[r] = fmaxf(fmaxf(st0[2*r], st0[2*r+1]), fmaxf(st1[2*r], st1[2*r+1]));
  float tm = fmaxf(fmaxf(fmaxf(m01[0],m01[1]), fmaxf(m01[2],m01[3])),
                   fmaxf(fmaxf(m01[4],m01[5]), fmaxf(m01[6],m01[7])));
  float mm = m_run;
  if (!__all(tm - m_run <= 8.f)){                 // first tile: inf/NaN -> rescale path
    float tg = fmaxf(tm, __shfl_xor(tm, 32));     // partner lane = same q row, other k-half
    const float mn = fmaxf(m_run, tg);
    const float fac = EXP2(m_run - mn);           // first tile: exp2(-inf)=0
    l_run *= fac;
    #pragma unroll
    for (int r = 0; r < 16; ++r){ acc0[r] *= fac; acc1[r] *= fac; }
    m_run = mn; mm = mn;
  }
  float ps0 = 0.f, ps1 = 0.f, ps2 = 0.f, ps3 = 0.f;
  #pragma unroll
  for (int r = 0; r < 4; ++r){
    float e0 = EXP2(st0[4*r+0]-mm), e1 = EXP2(st0[4*r+1]-mm);
    float e2 = EXP2(st0[4*r+2]-mm), e3 = EXP2(st0[4*r+3]-mm);
    float f0 = EXP2(st1[4*r+0]-mm), f1 = EXP2(st1[4*r+1]-mm);
    float f2 = EXP2(st1[4*r+2]-mm), f3 = EXP2(st1[4*r+3]-mm);
    ps0 += e0 + f0; ps1 += e1 + f1; ps2 += e2 + f2; ps3 += e3 + f3;
    st0[4*r+0]=e0; st0[4*r+1]=e1; st0[4*r+2]=e2; st0[4*r+3]=e3;
    st1[4*r+0]=f0; st1[4*r+1]=f1; st1[4*r+2]=f2; st1[4*r+3]=f3;
  }
  l_run += (ps0 + ps1) + (ps2 + ps3);             // lane-local partial; cross-half at epilogue
  #pragma unroll
  for (int m = 0; m < 2; ++m){
    bf16x8 t0, t1;
    #pragma unroll
    for (int i = 0; i < 8; ++i){
      t0[i] = (short)f2bfc(st0[8*m+i]);
      t1[i] = (short)f2bfc(st1[8*m+i]);
    }
    pb[m] = t0; pb[2+m] = t1;
  }
}

// ---------------- causal flash attention (32x32 MFMA) — measured-best (R11/R16) ----------------
// Grid: 256 linear; decode L -> xcd=L&7, idx=L>>3, bh=xcd*8+(idx&7), pair=idx>>3.
// Each block: TWO q-blocks (7-pair, then pair), QBLK=256 -> exactly 18 rounds
// per block: placement-independent balance; XCD grouping keeps K/V L2-resident.
// Block: 8 waves x 512 thr; wave owns 32 q rows. KVBLK=128, double-buffered
// prefetch, one barrier per round, compile-time buffer parity (ntiles even).
// QK^T: S^T = mfma_32x32x16(K,Q) with sigma-permuted K placement in LDS
// (lane's S regs = contiguous PV B-frags, zero cross-lane movement).
// PV: O^T = V^T @ P^T (full rate). Denominator: lane-local VALU partials +
// one shfl_xor(32) at epilogue.
__global__ __launch_bounds__(512, 2) void attn_kernel(const unsigned short* __restrict__ QK,
                                                      const unsigned short* __restrict__ Vt,
                                                      unsigned short* __restrict__ Og)
{
  __shared__ __attribute__((aligned(16))) unsigned short k_lds[2][128*64];
  __shared__ __attribute__((aligned(16))) unsigned short v_lds[2][64*128];
  const int tid = threadIdx.x;
  const int w = tid >> 6, l = tid & 63;
  const int h1 = l >> 5, lq = l & 31;
  const int L = blockIdx.x;
  const int xcd = L & 7, idx = L >> 3;
  const int bh = xcd*8 + (idx & 7);
  const int pair = idx >> 3;                            // 0..3
  const int b = bh >> 4, h = bh & 15;
  const size_t baseK = (size_t)(b*T_SEQ)*DM2 + 1024 + h*DKH;
  const size_t baseV = (size_t)(h*DKH)*MROWS + (size_t)b*T_SEQ;

  const int cA = tid, cB = tid + 512;
  const int krA = cA >> 3, krB = cB >> 3;
  const int kiA = (cA & 7) ^ (krA & 7), kiB = (cB & 7) ^ (krB & 7);
  const int kvA = 32*(krA >> 5) + 16*((krA >> 4) & 1) + 8*((krA >> 2) & 1) + 4*((krA >> 3) & 1) + (krA & 3);
  const int kvB = 32*(krB >> 5) + 16*((krB >> 4) & 1) + 8*((krB >> 2) & 1) + 4*((krB >> 3) & 1) + (krB & 3);
  const int vrA = cA >> 4, vgA = (cA & 15) ^ (vrA & 15);
  const int vrB = cB >> 4, vgB = (cB & 15) ^ (vrB & 15);

  auto STAGE = [&](int jt, int buf){
    const int j0s = jt * 128;
    gload_lds16(QK + baseK + (size_t)(j0s + kvA)*DM2 + kiA*8, &k_lds[buf][cA*8]);
    gload_lds16(QK + baseK + (size_t)(j0s + kvB)*DM2 + kiB*8, &k_lds[buf][cB*8]);
    gload_lds16(Vt + baseV + (size_t)vrA*MROWS + j0s + vgA*8, &v_lds[buf][cA*8]);
    gload_lds16(Vt + baseV + (size_t)vrB*MROWS + j0s + vgB*8, &v_lds[buf][cB*8]);
  };

#define ROUND(JT, CUR) do{                                                        \
    const int jt_ = (JT);                                                         \
    if (jt_ + 1 < ntiles) STAGE(jt_ + 1, (CUR)^1);                                \
    const int j0_ = jt_ * 128;                                                    \
    _Pragma("unroll")                                                             \
    for (int h2 = 0; h2 < 2; ++h2){                                               \
      if (j0_ + 64*h2 <= qhi){                                                    \
        f32x16 st0 = {}, st1 = {};                                                \
        __builtin_amdgcn_s_setprio(1);                                            \
        _Pragma("unroll")                                                         \
        for (int s = 0; s < 4; ++s){                                              \
          const int r0_ = 64*h2 + lq, r1_ = r0_ + 32;                             \
          bf16x8 kf0 = *(const bf16x8*)((const char*)k_lds[CUR] + r0_*128 + (((2*s + h1) ^ (r0_ & 7)) << 4)); \
          bf16x8 kf1 = *(const bf16x8*)((const char*)k_lds[CUR] + r1_*128 + (((2*s + h1) ^ (r1_ & 7)) << 4)); \
          st0 = MFMA32(kf0, qf[s], st0);                                          \
          st1 = MFMA32(kf1, qf[s], st1);                                          \
        }                                                                         \
        __builtin_amdgcn_s_setprio(0);                                            \
        bf16x8 pb[4];                                                             \
        half_softmax(st0, st1, m_run, l_run, acc0, acc1, pb,                      \
                     j0_ + 64*h2 + 8*h1, qg, (j0_ + 64*h2 + 63) <= qlo);          \
        __builtin_amdgcn_s_setprio(1);                                            \
        _Pragma("unroll")                                                         \
        for (int jl = 0; jl < 4; ++jl){                                           \
          const int vr0 = lq, vr1 = 32 + lq;                                      \
          bf16x8 vf0 = *(const bf16x8*)((const char*)v_lds[CUR] + vr0*256 + (((2*(4*h2 + jl) + h1) ^ (vr0 & 15)) << 4)); \
          bf16x8 vf1 = *(const bf16x8*)((const char*)v_lds[CUR] + vr1*256 + (((2*(4*h2 + jl) + h1) ^ (vr1 & 15)) << 4)); \
          acc0 = MFMA32(vf0, pb[jl], acc0);                                       \
          acc1 = MFMA32(vf1, pb[jl], acc1);                                       \
        }                                                                         \
        __builtin_amdgcn_s_setprio(0);                                            \
      }                                                                           \
    }                                                                             \
    __syncthreads();                                                              \
  } while(0)

  #pragma unroll 1
  for (int seg = 0; seg < 2; ++seg){
    const int qblk = seg ? pair : (7 - pair);           // heavy then light: 18 rounds total
    const int q0 = qblk * 256;
    const int qlo = q0 + 32*w;
    const int qhi = qlo + 31;
    const int qg = qlo + lq;
    const size_t rowQ = (size_t)(b*T_SEQ + qg)*DM2 + h*DKH;
    bf16x8 qf[4];
    #pragma unroll
    for (int s = 0; s < 4; ++s)
      qf[s] = *(const bf16x8*)(QK + rowQ + 16*s + 8*h1);
    float m_run = NEG_INF, l_run = 0.f;
    f32x16 acc0 = {}, acc1 = {};
    const int ntiles = 2*qblk + 2;                      // even -> clean buffer pairing

    STAGE(0, 0);
    __syncthreads();

    #pragma unroll 1
    for (int jt = 0; jt < ntiles; jt += 2){
      ROUND(jt, 0);
      ROUND(jt + 1, 1);
    }

    const float ls = l_run + __shfl_xor(l_run, 32);
    const float inv = 1.f / ls;
    const size_t rowO = (size_t)(b*T_SEQ + qg)*DM + h*DKH;
    #pragma unroll
    for (int d = 0; d < 2; ++d){
      const f32x16& Aq = d ? acc1 : acc0;
      #pragma unroll
      for (int bb = 0; bb < 4; ++bb){
        unsigned u0 = (unsigned)f2bfc(Aq[4*bb+0]*inv) | ((unsigned)f2bfc(Aq[4*bb+1]*inv) << 16);
        unsigned u1 = (unsigned)f2bfc(Aq[4*bb+2]*inv) | ((unsigned)f2bfc(Aq[4*bb+3]*inv) << 16);
        uint2 uv; uv.x = u0; uv.y = u1;
        *(uint2*)(Og + rowO + 32*d + 8*bb + 4*h1) = uv;
      }
    }
    // seg boundary: ROUND ends with __syncthreads -> safe to re-STAGE buf0.
  }
#undef ROUND
}

// ---------------- launch ----------------
extern "C" void kernel_launch(void* const* d_in, const int* in_sizes, int n_in,
                              void* d_out, int out_size, void* d_ws, size_t ws_size,
                              hipStream_t stream)
{
  (void)in_sizes; (void)n_in; (void)out_size; (void)ws_size;
  const float* H  = (const float*)d_in[0];
  const float* Wq = (const float*)d_in[1];
  const float* Wk = (const float*)d_in[2];
  const float* Wv = (const float*)d_in[3];
  const float* Wo = (const float*)d_in[4];
  char* ws = (char*)d_ws;
  unsigned short* Hb   = (unsigned short*)(ws);
  unsigned short* Wqkt = (unsigned short*)(ws + 16777216);   // rows 0-1023: Wq^T (scaled), 1024-2047: Wk^T
  unsigned short* Wkt  = (unsigned short*)(ws + 18874368);
  unsigned short* Wvt  = (unsigned short*)(ws + 20971520);
  unsigned short* Wot  = (unsigned short*)(ws + 23068672);
  unsigned short* QKb  = (unsigned short*)(ws + 25165824);   // 32MB
  unsigned short* Vtb  = (unsigned short*)(ws + 58720256);
  unsigned short* Ab   = (unsigned short*)(ws + 75497472);

  convprep<<<6144, 256, 0, stream>>>(H, Wq, Wk, Wv, Wo,
                                     (u16x4*)Hb, Wqkt, Wkt, Wvt, Wot);
  gemm_qk8<<<256, 512, 0, stream>>>(Hb, Wqkt, QKb);
  gemm_vt<<<dim3(8,64), 256, 0, stream>>>(Wvt, Hb, Vtb);
  attn_kernel<<<dim3(256), 512, 0, stream>>>(QKb, Vtb, Ab);
  gemm_out<<<dim3(64,8), 256, 0, stream>>>(Ab, Wot, (float*)d_out);
}